// Round 4
// baseline (206.984 us; speedup 1.0000x reference)
//
#include <hip/hip_runtime.h>
#include <stdint.h>
#include <math.h>

#define SEQ 2048
#define NH 16
#define DM 1024

typedef __bf16 bf16x8 __attribute__((ext_vector_type(8)));
typedef float f32x4 __attribute__((ext_vector_type(4)));

// raw barrier / waitcnt: no compiler-inserted vmcnt(0) drain (the m97 stall)
#define ASM_VMCNT0  asm volatile("s_waitcnt vmcnt(0)" ::: "memory")
#define ASM_BARRIER asm volatile("s_barrier" ::: "memory")

__device__ __forceinline__ unsigned short f2bf(float f) {
  union { float f; unsigned u; } v; v.f = f;
  unsigned r = v.u + 0x7fffu + ((v.u >> 16) & 1u);
  return (unsigned short)(r >> 16);
}
__device__ __forceinline__ unsigned pk2(float a, float b) {
  return (unsigned)f2bf(a) | ((unsigned)f2bf(b) << 16);
}
__device__ __forceinline__ void load_lds16(const void* g, void* l) {
  __builtin_amdgcn_global_load_lds((__attribute__((address_space(1))) void*)g,
                                   (__attribute__((address_space(3))) void*)l,
                                   16, 0, 0);
}

// ---------------------------------------------------------------------------
// fp32 -> bf16 conversion: x (4M) + wq/wk/wv/wo (1M each) into ws.
// ---------------------------------------------------------------------------
__global__ void cvt_all(const float* __restrict__ x, const float* __restrict__ wq,
                        const float* __restrict__ wk, const float* __restrict__ wv,
                        const float* __restrict__ wo, unsigned short* __restrict__ ws) {
  const int i = blockIdx.x * blockDim.x + threadIdx.x;
  const int off = i * 4;
  const float* src;
  unsigned short* dst;
  if (off < 4194304) {
    src = x + off;  dst = ws + off;
  } else {
    const int r = off - 4194304;
    const int w = r >> 20, o = r & 1048575;
    const float* tabs[4] = {wq, wk, wv, wo};
    src = tabs[w] + o;  dst = ws + 4194304 + (w << 20) + o;
  }
  const float4 v = *(const float4*)src;
  ushort4 u;
  u.x = f2bf(v.x); u.y = f2bf(v.y); u.z = f2bf(v.z); u.w = f2bf(v.w);
  *(ushort4*)dst = u;
}

// ---------------------------------------------------------------------------
// Fused QKV projection: C = x (4096x1024) @ W3^T (W3 = [wq;wk;wv], 3072x1024).
// 128x128 tiles, grid (24, 32). Double-buffered LDS + raw-barrier async K-loop.
// n in [0,1024): RoPE -> Qr (b,h,s,d); [1024,2048): RoPE -> Kr; else Vt (b,h,d,s).
// ---------------------------------------------------------------------------
__launch_bounds__(256, 2)
__global__ void gemm_qkv(const unsigned short* __restrict__ X,
                         const unsigned short* __restrict__ W3,
                         unsigned short* __restrict__ Qr,
                         unsigned short* __restrict__ Kr,
                         unsigned short* __restrict__ Vt,
                         const int* __restrict__ tp) {
  __shared__ __align__(16) char smem[32768];
  // buf b: A at b*8192, B at 16384 + b*8192

  const int t = threadIdx.x;
  const int lane = t & 63, wave = t >> 6;
  const int quad = lane >> 4, l16 = lane & 15;
  const int m0 = blockIdx.y * 128, n0 = blockIdx.x * 128;
  const int wm = (wave >> 1) * 64, wn = (wave & 1) * 64;

  f32x4 acc[4][4];
#pragma unroll
  for (int i = 0; i < 4; i++)
#pragma unroll
    for (int j = 0; j < 4; j++) { acc[i][j][0]=0.f; acc[i][j][1]=0.f; acc[i][j][2]=0.f; acc[i][j][3]=0.f; }

  const int rr = t >> 2;
  const int cc = (t & 3) * 8;

#define QKV_STAGE(bufidx, k0_) do {                                               \
    char* a_ = smem + (bufidx) * 8192;                                            \
    char* b_ = smem + 16384 + (bufidx) * 8192;                                    \
    _Pragma("unroll")                                                             \
    for (int i_ = 0; i_ < 2; i_++) {                                              \
      load_lds16(X  + (uint64_t)(m0 + i_ * 64 + rr) * 1024 + (k0_) + cc,          \
                 a_ + i_ * 4096 + wave * 1024);                                   \
      load_lds16(W3 + (uint64_t)(n0 + i_ * 64 + rr) * 1024 + (k0_) + cc,          \
                 b_ + i_ * 4096 + wave * 1024);                                   \
    }                                                                             \
  } while (0)

  QKV_STAGE(0, 0);

  for (int k0 = 0; k0 < 1024; k0 += 32) {
    const int buf = (k0 >> 5) & 1;
    ASM_VMCNT0;     // my stage(k0) loads done (issued one full iter ago)
    ASM_BARRIER;    // everyone's stage(k0) done; everyone finished reading buf^1
    if (k0 + 32 < 1024) QKV_STAGE(buf ^ 1, k0 + 32);
    char* As = smem + buf * 8192;
    char* Bs = smem + 16384 + buf * 8192;

    bf16x8 af[4], bfr[4];
#pragma unroll
    for (int i = 0; i < 4; i++) {
      af[i]  = *(const bf16x8*)(As + (wm + i * 16 + l16) * 64 + quad * 16);
      bfr[i] = *(const bf16x8*)(Bs + (wn + i * 16 + l16) * 64 + quad * 16);
    }
#pragma unroll
    for (int i = 0; i < 4; i++)
#pragma unroll
      for (int j = 0; j < 4; j++)
        acc[i][j] = __builtin_amdgcn_mfma_f32_16x16x32_bf16(af[i], bfr[j], acc[i][j], 0, 0, 0);
  }
#undef QKV_STAGE

  if (n0 < 2048) {
    // Q or K with RoPE. n = n0+wn+j*16+l16; d = n&63; pairs via lane^1.
    unsigned short* dst = (n0 < 1024) ? Qr : Kr;
    float fr[4]; int dd[4], hh[4];
#pragma unroll
    for (int j = 0; j < 4; j++) {
      const int n = n0 + wn + j * 16 + l16;
      dd[j] = n & 63;
      hh[j] = (n & 1023) >> 6;
      // 10000^(-(d&~1)/64) / (2*pi)
      fr[j] = __builtin_amdgcn_exp2f(-0.20762050594f * (float)(dd[j] & ~1)) * 0.15915494309f;
    }
    const float sgnodd = (l16 & 1) ? 1.f : -1.f;
#pragma unroll
    for (int i = 0; i < 4; i++) {
#pragma unroll
      for (int r = 0; r < 4; r++) {
        const int m = m0 + wm + i * 16 + quad * 4 + r;
        const int s = m & 2047, b = m >> 11;
        const float posf = (float)tp[m];
#pragma unroll
        for (int j = 0; j < 4; j++) {
          const float v = acc[i][j][r];
          const float p = __shfl_xor(v, 1);
          float rev = posf * fr[j];
          rev -= floorf(rev);
          float sn, cs;
          asm("v_sin_f32 %0, %1" : "=v"(sn) : "v"(rev));
          asm("v_cos_f32 %0, %1" : "=v"(cs) : "v"(rev));
          const float rv = fmaf(v, cs, p * sn * sgnodd);
          dst[((uint64_t)((b * NH + hh[j]) * SEQ + s)) * 64 + dd[j]] = f2bf(rv);
        }
      }
    }
  } else {
    // V -> Vt (b,h,d,s), pack 4 consecutive s as one 8B store
#pragma unroll
    for (int i = 0; i < 4; i++) {
      const int m = m0 + wm + i * 16 + quad * 4;
      const int s = m & 2047, b = m >> 11;
#pragma unroll
      for (int j = 0; j < 4; j++) {
        const int n = n0 - 2048 + wn + j * 16 + l16;
        const int h = n >> 6, d = n & 63;
        uint2 w;
        w.x = pk2(acc[i][j][0], acc[i][j][1]);
        w.y = pk2(acc[i][j][2], acc[i][j][3]);
        *(uint2*)(Vt + ((uint64_t)((b * NH + h) * 64 + d)) * SEQ + s) = w;
      }
    }
  }
}

// ---------------------------------------------------------------------------
// Output projection: C = At (4096x1024) @ wo^T, fp32 out. 128x64 tiles,
// grid (16, 32). Double-buffered LDS + raw-barrier async K-loop.
// ---------------------------------------------------------------------------
__launch_bounds__(256, 2)
__global__ void gemm_ao(const unsigned short* __restrict__ A,
                        const unsigned short* __restrict__ B,
                        float* __restrict__ C) {
  __shared__ __align__(16) char smem[24576];
  // buf b: A at b*8192, B at 16384 + b*4096

  const int t = threadIdx.x;
  const int lane = t & 63, wave = t >> 6;
  const int quad = lane >> 4, l16 = lane & 15;
  const int m0 = blockIdx.y * 128, n0 = blockIdx.x * 64;
  const int wm = (wave >> 1) * 64, wn = (wave & 1) * 32;

  f32x4 acc[4][2];
#pragma unroll
  for (int i = 0; i < 4; i++)
#pragma unroll
    for (int j = 0; j < 2; j++) { acc[i][j][0]=0.f; acc[i][j][1]=0.f; acc[i][j][2]=0.f; acc[i][j][3]=0.f; }

  const int rr = t >> 2;
  const int cc = (t & 3) * 8;

#define AO_STAGE(bufidx, k0_) do {                                                \
    char* a_ = smem + (bufidx) * 8192;                                            \
    char* b_ = smem + 16384 + (bufidx) * 4096;                                    \
    _Pragma("unroll")                                                             \
    for (int i_ = 0; i_ < 2; i_++)                                                \
      load_lds16(A + (uint64_t)(m0 + i_ * 64 + rr) * 1024 + (k0_) + cc,           \
                 a_ + i_ * 4096 + wave * 1024);                                   \
    load_lds16(B + (uint64_t)(n0 + rr) * 1024 + (k0_) + cc, b_ + wave * 1024);    \
  } while (0)

  AO_STAGE(0, 0);

  for (int k0 = 0; k0 < 1024; k0 += 32) {
    const int buf = (k0 >> 5) & 1;
    ASM_VMCNT0;
    ASM_BARRIER;
    if (k0 + 32 < 1024) AO_STAGE(buf ^ 1, k0 + 32);
    char* As = smem + buf * 8192;
    char* Bs = smem + 16384 + buf * 4096;

    bf16x8 af[4], bfr[2];
#pragma unroll
    for (int i = 0; i < 4; i++)
      af[i] = *(const bf16x8*)(As + (wm + i * 16 + l16) * 64 + quad * 16);
#pragma unroll
    for (int j = 0; j < 2; j++)
      bfr[j] = *(const bf16x8*)(Bs + (wn + j * 16 + l16) * 64 + quad * 16);
#pragma unroll
    for (int i = 0; i < 4; i++)
#pragma unroll
      for (int j = 0; j < 2; j++)
        acc[i][j] = __builtin_amdgcn_mfma_f32_16x16x32_bf16(af[i], bfr[j], acc[i][j], 0, 0, 0);
  }
#undef AO_STAGE

#pragma unroll
  for (int i = 0; i < 4; i++)
#pragma unroll
    for (int j = 0; j < 2; j++)
#pragma unroll
      for (int r = 0; r < 4; r++) {
        const int m = m0 + wm + i * 16 + quad * 4 + r;
        const int n = n0 + wn + j * 16 + l16;
        C[(uint64_t)m * DM + n] = acc[i][j][r];
      }
}

// ---------------------------------------------------------------------------
// Flash attention, transposed scheme. Block = (64 q) x (b*h); 4 waves, wave
// owns 16 q (q = l16). S^T = K Q^T -> softmax (q per lane) -> O^T += V^T P^T.
// XOR-swizzled LDS, double-buffered K/V, raw-barrier async staging:
// loads for tile kt+1 stay in flight across the whole kt compute.
// ---------------------------------------------------------------------------
__launch_bounds__(256, 4)
__global__ void flash_attn(const unsigned short* __restrict__ Q,
                           const unsigned short* __restrict__ K,
                           const unsigned short* __restrict__ Vt,
                           unsigned short* __restrict__ Oa) {
  __shared__ __align__(16) char smem[40960];
  // Ks buf b: smem + b*8192          (64 key-rows x 128B, chunks swizzled)
  // Vs buf b: smem + 16384 + b*8192  (64 d-rows   x 128B, chunks swizzled)
  // Ps      : smem + 32768 + wave*2048 (16 q-rows x 128B, chunks swizzled)

  const int t = threadIdx.x;
  const int lane = t & 63, wave = t >> 6;
  const int quad = lane >> 4, l16 = lane & 15;
  const int bx = blockIdx.x;
  const int qt = (bx & 1) ? (31 - (bx >> 1)) : (bx >> 1);  // pair long+short
  const int bh = blockIdx.y;
  const int qbase = qt * 64;
  const uint64_t base = (uint64_t)bh * (SEQ * 64);
  const int qg = qbase + wave * 16 + l16;  // this lane's q row

  // Q B-fragment: lane n=q=l16, k=d=kk*32+quad*8+j
  bf16x8 qf[2];
  {
    const unsigned short* qp = Q + base + (uint64_t)qg * 64 + quad * 8;
    qf[0] = *(const bf16x8*)qp;
    qf[1] = *(const bf16x8*)(qp + 32);
  }

  f32x4 o[4];
#pragma unroll
  for (int i = 0; i < 4; i++) { o[i][0]=0.f; o[i][1]=0.f; o[i][2]=0.f; o[i][3]=0.f; }
  float mI = -1e30f, lI = 0.f;

  const int srow = wave * 8 + (lane >> 3);             // staging row (+i*32)
  const int sc = ((lane & 7) ^ (lane >> 3)) * 8;       // swizzled chunk, shorts
  const int swz = (l16 & 7);                           // frag-read swizzle key
  char* ps = smem + 32768 + wave * 2048;

#define STAGE(bufidx, kb_) do {                                                   \
    char* kd_ = smem + (bufidx) * 8192;                                           \
    char* vd_ = smem + 16384 + (bufidx) * 8192;                                   \
    _Pragma("unroll")                                                             \
    for (int i_ = 0; i_ < 2; i_++) {                                              \
      load_lds16(K  + base + (uint64_t)((kb_) + i_ * 32 + srow) * 64 + sc,        \
                 kd_ + i_ * 4096 + wave * 1024);                                  \
      load_lds16(Vt + base + (uint64_t)(i_ * 32 + srow) * SEQ + (kb_) + sc,       \
                 vd_ + i_ * 4096 + wave * 1024);                                  \
    }                                                                             \
  } while (0)

  STAGE(0, 0);

  for (int kt = 0; kt <= qt; kt++) {
    const int kb = kt * 64;
    const int buf = kt & 1;
    ASM_VMCNT0;     // my stage(kt) done (issued a full iteration ago; Q loads on kt=0)
    ASM_BARRIER;    // all stages visible; all waves done reading buf^1
    if (kt < qt) STAGE(buf ^ 1, kb + 64);   // stays in flight across this compute
    char* ks = smem + buf * 8192;
    char* vs = smem + 16384 + buf * 8192;
    const bool diag = (kt == qt);
    const int nbmax = diag ? (wave + 1) : 4;

    // S^T = K Q^T : A=K-frag (m=key), B=Q-frag (n=q). C: key=quad*4+r, q=l16.
    f32x4 sf[4];
#pragma unroll
    for (int nb = 0; nb < 4; nb++) {
      if (nb < nbmax) {
        f32x4 s; s[0]=0.f; s[1]=0.f; s[2]=0.f; s[3]=0.f;
#pragma unroll
        for (int kk = 0; kk < 2; kk++) {
          bf16x8 kfr = *(const bf16x8*)(ks + (nb * 16 + l16) * 128 + (((kk * 4 + quad) ^ swz) * 16));
          s = __builtin_amdgcn_mfma_f32_16x16x32_bf16(kfr, qf[kk], s, 0, 0, 0);
        }
        sf[nb] = s;
      } else {
        sf[nb][0] = -1e30f; sf[nb][1] = -1e30f; sf[nb][2] = -1e30f; sf[nb][3] = -1e30f;
      }
    }
    if (diag) {
#pragma unroll
      for (int nb = 0; nb < 4; nb++)
#pragma unroll
        for (int r = 0; r < 4; r++)
          if (kb + nb * 16 + quad * 4 + r > qg) sf[nb][r] = -1e30f;
    }

    // online softmax; q lives in lane (l16), key-partials across quads
    float mx = sf[0][0];
#pragma unroll
    for (int nb = 0; nb < 4; nb++)
#pragma unroll
      for (int r = 0; r < 4; r++) mx = fmaxf(mx, sf[nb][r]);
    mx = fmaxf(mx, __shfl_xor(mx, 16));
    mx = fmaxf(mx, __shfl_xor(mx, 32));
    const float mnew = fmaxf(mI, mx);
    const float c1 = 0.18033688011f;  // log2(e)/8
    const float mc = mnew * c1;
    const float alpha = __builtin_amdgcn_exp2f(mI * c1 - mc);
    mI = mnew;
    float ls = 0.f;
#pragma unroll
    for (int nb = 0; nb < 4; nb++)
#pragma unroll
      for (int r = 0; r < 4; r++) {
        const float p = __builtin_amdgcn_exp2f(sf[nb][r] * c1 - mc);
        sf[nb][r] = p;
        ls += p;
      }
    lI = lI * alpha + ls;   // lane-local partial (this quad's keys); reduced at end
#pragma unroll
    for (int db = 0; db < 4; db++)
#pragma unroll
      for (int r = 0; r < 4; r++) o[db][r] *= alpha;

    // P^T -> Ps (row=q(l16), 64 keys, swizzled chunks); vectorized b64 writes
#pragma unroll
    for (int nb = 0; nb < 4; nb++) {
      uint2 pv;
      pv.x = pk2(sf[nb][0], sf[nb][1]);
      pv.y = pk2(sf[nb][2], sf[nb][3]);
      *(uint2*)(ps + l16 * 128 + (((nb * 2 + (quad >> 1)) ^ swz) * 16) + (quad & 1) * 8) = pv;
    }
    // wave-private region: compiler's lgkmcnt ordering suffices, no barrier.

    // O^T += V^T P^T : A=V-frag (m=d), B=P-frag (n=q)
    const int kkmax = diag ? ((wave >> 1) + 1) : 2;
    for (int kk = 0; kk < kkmax; kk++) {
      bf16x8 pf = *(const bf16x8*)(ps + l16 * 128 + (((kk * 4 + quad) ^ swz) * 16));
#pragma unroll
      for (int db = 0; db < 4; db++) {
        bf16x8 vf = *(const bf16x8*)(vs + (db * 16 + l16) * 128 + (((kk * 4 + quad) ^ swz) * 16));
        o[db] = __builtin_amdgcn_mfma_f32_16x16x32_bf16(vf, pf, o[db], 0, 0, 0);
      }
    }
  }
#undef STAGE

  // final l reduction across quads, normalize, store At (b,s,h,d)
  lI += __shfl_xor(lI, 16);
  lI += __shfl_xor(lI, 32);
  const float invl = 1.0f / lI;
  const int b = bh >> 4, h = bh & 15;
  unsigned short* orow = Oa + ((uint64_t)(b * SEQ + qg)) * DM + h * 64 + quad * 4;
#pragma unroll
  for (int db = 0; db < 4; db++) {
    uint2 w;
    w.x = pk2(o[db][0] * invl, o[db][1] * invl);
    w.y = pk2(o[db][2] * invl, o[db][3] * invl);
    *(uint2*)(orow + db * 16) = w;
  }
}

extern "C" void kernel_launch(void* const* d_in, const int* in_sizes, int n_in,
                              void* d_out, int out_size, void* d_ws, size_t ws_size,
                              hipStream_t stream) {
  const float* x  = (const float*)d_in[0];
  const int* tp   = (const int*)d_in[1];
  const float* wq = (const float*)d_in[2];
  const float* wk = (const float*)d_in[3];
  const float* wv = (const float*)d_in[4];
  const float* wo = (const float*)d_in[5];
  float* out = (float*)d_out;

  unsigned short* ws = (unsigned short*)d_ws;
  unsigned short* xb  = ws;                   // (b,s,dm) bf16        8 MB
  unsigned short* w3b = ws + 4194304;         // [wq;wk;wv] 3072x1024 6 MB
  unsigned short* wob = ws + 7340032;         // 2 MB
  unsigned short* Qr  = ws + 8388608;         // (b,h,s,64)  8 MB
  unsigned short* Kr  = ws + 12582912;        // (b,h,s,64)  8 MB
  unsigned short* Vt  = ws + 16777216;        // (b,h,64,s)  8 MB
  unsigned short* At  = ws + 20971520;        // (b,s,h*64)  8 MB

  cvt_all<<<8192, 256, 0, stream>>>(x, wq, wk, wv, wo, ws);
  gemm_qkv<<<dim3(24, 32), 256, 0, stream>>>(xb, w3b, Qr, Kr, Vt, tp);
  flash_attn<<<dim3(32, 32), 256, 0, stream>>>(Qr, Kr, Vt, At);
  gemm_ao<<<dim3(16, 32), 256, 0, stream>>>(At, wob, out);
}

// Round 5
// 181.930 us; speedup vs baseline: 1.1377x; 1.1377x over previous
//
#include <hip/hip_runtime.h>
#include <stdint.h>
#include <math.h>

#define SEQ 2048
#define NH 16
#define DM 1024

typedef __bf16 bf16x8 __attribute__((ext_vector_type(8)));
typedef __bf16 bf16x2 __attribute__((ext_vector_type(2)));
typedef float f32x4 __attribute__((ext_vector_type(4)));
typedef float f32x2 __attribute__((ext_vector_type(2)));

// raw barrier / waitcnt: no compiler-inserted vmcnt(0) drain
#define ASM_VMCNT0  asm volatile("s_waitcnt vmcnt(0)" ::: "memory")
#define ASM_BARRIER asm volatile("s_barrier" ::: "memory")

__device__ __forceinline__ unsigned short f2bf(float f) {
  union { float f; unsigned u; } v; v.f = f;
  unsigned r = v.u + 0x7fffu + ((v.u >> 16) & 1u);
  return (unsigned short)(r >> 16);
}
__device__ __forceinline__ unsigned pk2(float a, float b) {
  f32x2 v = {a, b};
  bf16x2 r = __builtin_convertvector(v, bf16x2);  // v_cvt_pk_bf16_f32 on gfx950
  union { bf16x2 h; unsigned u; } c; c.h = r;
  return c.u;
}
__device__ __forceinline__ void load_lds16(const void* g, void* l) {
  __builtin_amdgcn_global_load_lds((__attribute__((address_space(1))) void*)g,
                                   (__attribute__((address_space(3))) void*)l,
                                   16, 0, 0);
}

// ---------------------------------------------------------------------------
// fp32 -> bf16 conversion: x (4M) + wq/wk/wv/wo (1M each) into ws.
// ---------------------------------------------------------------------------
__global__ void cvt_all(const float* __restrict__ x, const float* __restrict__ wq,
                        const float* __restrict__ wk, const float* __restrict__ wv,
                        const float* __restrict__ wo, unsigned short* __restrict__ ws) {
  const int i = blockIdx.x * blockDim.x + threadIdx.x;
  const int off = i * 4;
  const float* src;
  unsigned short* dst;
  if (off < 4194304) {
    src = x + off;  dst = ws + off;
  } else {
    const int r = off - 4194304;
    const int w = r >> 20, o = r & 1048575;
    const float* tabs[4] = {wq, wk, wv, wo};
    src = tabs[w] + o;  dst = ws + 4194304 + (w << 20) + o;
  }
  const float4 v = *(const float4*)src;
  uint2 u;
  u.x = pk2(v.x, v.y);
  u.y = pk2(v.z, v.w);
  *(uint2*)dst = u;
}

// ---------------------------------------------------------------------------
// Fused QKV projection: C = x (4096x1024) @ W3^T (W3 = [wq;wk;wv], 3072x1024).
// 128x128 tiles, grid (24, 32). Double-buffered LDS + raw-barrier async K-loop.
// n in [0,1024): RoPE -> Qr (b,h,s,d); [1024,2048): RoPE -> Kr; else Vt (b,h,d,s).
// ---------------------------------------------------------------------------
__launch_bounds__(256, 2)
__global__ void gemm_qkv(const unsigned short* __restrict__ X,
                         const unsigned short* __restrict__ W3,
                         unsigned short* __restrict__ Qr,
                         unsigned short* __restrict__ Kr,
                         unsigned short* __restrict__ Vt,
                         const int* __restrict__ tp) {
  __shared__ __align__(16) char smem[32768];

  const int t = threadIdx.x;
  const int lane = t & 63, wave = t >> 6;
  const int quad = lane >> 4, l16 = lane & 15;
  const int m0 = blockIdx.y * 128, n0 = blockIdx.x * 128;
  const int wm = (wave >> 1) * 64, wn = (wave & 1) * 64;

  f32x4 acc[4][4];
#pragma unroll
  for (int i = 0; i < 4; i++)
#pragma unroll
    for (int j = 0; j < 4; j++) { acc[i][j][0]=0.f; acc[i][j][1]=0.f; acc[i][j][2]=0.f; acc[i][j][3]=0.f; }

  const int rr = t >> 2;
  const int cc = (t & 3) * 8;

#define QKV_STAGE(bufidx, k0_) do {                                               \
    char* a_ = smem + (bufidx) * 8192;                                            \
    char* b_ = smem + 16384 + (bufidx) * 8192;                                    \
    _Pragma("unroll")                                                             \
    for (int i_ = 0; i_ < 2; i_++) {                                              \
      load_lds16(X  + (uint64_t)(m0 + i_ * 64 + rr) * 1024 + (k0_) + cc,          \
                 a_ + i_ * 4096 + wave * 1024);                                   \
      load_lds16(W3 + (uint64_t)(n0 + i_ * 64 + rr) * 1024 + (k0_) + cc,          \
                 b_ + i_ * 4096 + wave * 1024);                                   \
    }                                                                             \
  } while (0)

  QKV_STAGE(0, 0);

  for (int k0 = 0; k0 < 1024; k0 += 32) {
    const int buf = (k0 >> 5) & 1;
    ASM_VMCNT0;
    ASM_BARRIER;
    if (k0 + 32 < 1024) QKV_STAGE(buf ^ 1, k0 + 32);
    char* As = smem + buf * 8192;
    char* Bs = smem + 16384 + buf * 8192;

    bf16x8 af[4], bfr[4];
#pragma unroll
    for (int i = 0; i < 4; i++) {
      af[i]  = *(const bf16x8*)(As + (wm + i * 16 + l16) * 64 + quad * 16);
      bfr[i] = *(const bf16x8*)(Bs + (wn + i * 16 + l16) * 64 + quad * 16);
    }
#pragma unroll
    for (int i = 0; i < 4; i++)
#pragma unroll
      for (int j = 0; j < 4; j++)
        acc[i][j] = __builtin_amdgcn_mfma_f32_16x16x32_bf16(af[i], bfr[j], acc[i][j], 0, 0, 0);
  }
#undef QKV_STAGE

  if (n0 < 2048) {
    // Q or K with RoPE. n = n0+wn+j*16+l16; d = n&63; pairs via lane^1.
    unsigned short* dst = (n0 < 1024) ? Qr : Kr;
    float fr[4]; int dd[4], hh[4];
#pragma unroll
    for (int j = 0; j < 4; j++) {
      const int n = n0 + wn + j * 16 + l16;
      dd[j] = n & 63;
      hh[j] = (n & 1023) >> 6;
      // 10000^(-(d&~1)/64) / (2*pi)
      fr[j] = __builtin_amdgcn_exp2f(-0.20762050594f * (float)(dd[j] & ~1)) * 0.15915494309f;
    }
    const float sgnodd = (l16 & 1) ? 1.f : -1.f;
#pragma unroll
    for (int i = 0; i < 4; i++) {
#pragma unroll
      for (int r = 0; r < 4; r++) {
        const int m = m0 + wm + i * 16 + quad * 4 + r;
        const int s = m & 2047, b = m >> 11;
        const float posf = (float)tp[m];
#pragma unroll
        for (int j = 0; j < 4; j++) {
          const float v = acc[i][j][r];
          const float p = __shfl_xor(v, 1);
          float rev = posf * fr[j];
          rev -= floorf(rev);
          float sn, cs;
          asm("v_sin_f32 %0, %1" : "=v"(sn) : "v"(rev));
          asm("v_cos_f32 %0, %1" : "=v"(cs) : "v"(rev));
          const float rv = fmaf(v, cs, p * sn * sgnodd);
          dst[((uint64_t)((b * NH + hh[j]) * SEQ + s)) * 64 + dd[j]] = f2bf(rv);
        }
      }
    }
  } else {
    // V -> Vt (b,h,d,s), pack 4 consecutive s as one 8B store
#pragma unroll
    for (int i = 0; i < 4; i++) {
      const int m = m0 + wm + i * 16 + quad * 4;
      const int s = m & 2047, b = m >> 11;
#pragma unroll
      for (int j = 0; j < 4; j++) {
        const int n = n0 - 2048 + wn + j * 16 + l16;
        const int h = n >> 6, d = n & 63;
        uint2 w;
        w.x = pk2(acc[i][j][0], acc[i][j][1]);
        w.y = pk2(acc[i][j][2], acc[i][j][3]);
        *(uint2*)(Vt + ((uint64_t)((b * NH + h) * 64 + d)) * SEQ + s) = w;
      }
    }
  }
}

// ---------------------------------------------------------------------------
// Output projection: C = At (4096x1024) @ wo^T, fp32 out. 128x64 tiles,
// grid (16, 32). Double-buffered LDS + raw-barrier async K-loop.
// ---------------------------------------------------------------------------
__launch_bounds__(256, 2)
__global__ void gemm_ao(const unsigned short* __restrict__ A,
                        const unsigned short* __restrict__ B,
                        float* __restrict__ C) {
  __shared__ __align__(16) char smem[24576];

  const int t = threadIdx.x;
  const int lane = t & 63, wave = t >> 6;
  const int quad = lane >> 4, l16 = lane & 15;
  const int m0 = blockIdx.y * 128, n0 = blockIdx.x * 64;
  const int wm = (wave >> 1) * 64, wn = (wave & 1) * 32;

  f32x4 acc[4][2];
#pragma unroll
  for (int i = 0; i < 4; i++)
#pragma unroll
    for (int j = 0; j < 2; j++) { acc[i][j][0]=0.f; acc[i][j][1]=0.f; acc[i][j][2]=0.f; acc[i][j][3]=0.f; }

  const int rr = t >> 2;
  const int cc = (t & 3) * 8;

#define AO_STAGE(bufidx, k0_) do {                                                \
    char* a_ = smem + (bufidx) * 8192;                                            \
    char* b_ = smem + 16384 + (bufidx) * 4096;                                    \
    _Pragma("unroll")                                                             \
    for (int i_ = 0; i_ < 2; i_++)                                                \
      load_lds16(A + (uint64_t)(m0 + i_ * 64 + rr) * 1024 + (k0_) + cc,           \
                 a_ + i_ * 4096 + wave * 1024);                                   \
    load_lds16(B + (uint64_t)(n0 + rr) * 1024 + (k0_) + cc, b_ + wave * 1024);    \
  } while (0)

  AO_STAGE(0, 0);

  for (int k0 = 0; k0 < 1024; k0 += 32) {
    const int buf = (k0 >> 5) & 1;
    ASM_VMCNT0;
    ASM_BARRIER;
    if (k0 + 32 < 1024) AO_STAGE(buf ^ 1, k0 + 32);
    char* As = smem + buf * 8192;
    char* Bs = smem + 16384 + buf * 4096;

    bf16x8 af[4], bfr[2];
#pragma unroll
    for (int i = 0; i < 4; i++)
      af[i] = *(const bf16x8*)(As + (wm + i * 16 + l16) * 64 + quad * 16);
#pragma unroll
    for (int j = 0; j < 2; j++)
      bfr[j] = *(const bf16x8*)(Bs + (wn + j * 16 + l16) * 64 + quad * 16);
#pragma unroll
    for (int i = 0; i < 4; i++)
#pragma unroll
      for (int j = 0; j < 2; j++)
        acc[i][j] = __builtin_amdgcn_mfma_f32_16x16x32_bf16(af[i], bfr[j], acc[i][j], 0, 0, 0);
  }
#undef AO_STAGE

#pragma unroll
  for (int i = 0; i < 4; i++)
#pragma unroll
    for (int j = 0; j < 2; j++)
#pragma unroll
      for (int r = 0; r < 4; r++) {
        const int m = m0 + wm + i * 16 + quad * 4 + r;
        const int n = n0 + wn + j * 16 + l16;
        C[(uint64_t)m * DM + n] = acc[i][j][r];
      }
}

// ---------------------------------------------------------------------------
// Flash attention, transposed scheme. 1-D grid of 1024 blocks.
// CU-balance swizzle: CU c receives linear blocks {c, c+256, c+512, c+768};
// decode bh = lid&31 (same plane per CU -> L2 reuse), j = lid>>5,
// qt = {a, 15-a, 16+a, 31-a} for j = a+8p  -> per-CU work sum is constant (62).
// ---------------------------------------------------------------------------
__launch_bounds__(256, 4)
__global__ void flash_attn(const unsigned short* __restrict__ Q,
                           const unsigned short* __restrict__ K,
                           const unsigned short* __restrict__ Vt,
                           unsigned short* __restrict__ Oa) {
  __shared__ __align__(16) char smem[40960];
  // Ks buf b: smem + b*8192          (64 key-rows x 128B, chunks swizzled)
  // Vs buf b: smem + 16384 + b*8192  (64 d-rows   x 128B, chunks swizzled)
  // Ps      : smem + 32768 + wave*2048 (16 q-rows x 128B, chunks swizzled)

  const int t = threadIdx.x;
  const int lane = t & 63, wave = t >> 6;
  const int quad = lane >> 4, l16 = lane & 15;
  const int lid = blockIdx.x;
  const int bh = lid & 31;
  const int j = lid >> 5;
  const int a = j & 7, p = j >> 3;
  const int pb = (p >> 1) << 4;
  const int qt = (p & 1) ? (pb + 15 - a) : (pb + a);
  const int qbase = qt * 64;
  const uint64_t base = (uint64_t)bh * (SEQ * 64);
  const int qg = qbase + wave * 16 + l16;  // this lane's q row

  // Q B-fragment: lane n=q=l16, k=d=kk*32+quad*8+j
  bf16x8 qf[2];
  {
    const unsigned short* qp = Q + base + (uint64_t)qg * 64 + quad * 8;
    qf[0] = *(const bf16x8*)qp;
    qf[1] = *(const bf16x8*)(qp + 32);
  }

  f32x4 o[4];
#pragma unroll
  for (int i = 0; i < 4; i++) { o[i][0]=0.f; o[i][1]=0.f; o[i][2]=0.f; o[i][3]=0.f; }
  float mI = -1e30f, lI = 0.f;

  const int srow = wave * 8 + (lane >> 3);             // staging row (+i*32)
  const int sc = ((lane & 7) ^ (lane >> 3)) * 8;       // swizzled chunk, shorts
  const int swz = (l16 & 7);                           // frag-read swizzle key
  char* ps = smem + 32768 + wave * 2048;

#define STAGE(bufidx, kb_) do {                                                   \
    char* kd_ = smem + (bufidx) * 8192;                                           \
    char* vd_ = smem + 16384 + (bufidx) * 8192;                                   \
    _Pragma("unroll")                                                             \
    for (int i_ = 0; i_ < 2; i_++) {                                              \
      load_lds16(K  + base + (uint64_t)((kb_) + i_ * 32 + srow) * 64 + sc,        \
                 kd_ + i_ * 4096 + wave * 1024);                                  \
      load_lds16(Vt + base + (uint64_t)(i_ * 32 + srow) * SEQ + (kb_) + sc,       \
                 vd_ + i_ * 4096 + wave * 1024);                                  \
    }                                                                             \
  } while (0)

  STAGE(0, 0);

  for (int kt = 0; kt <= qt; kt++) {
    const int kb = kt * 64;
    const int buf = kt & 1;
    ASM_VMCNT0;     // my stage(kt) done (issued a full iteration ago)
    ASM_BARRIER;    // all stages visible; all waves done reading buf^1
    if (kt < qt) STAGE(buf ^ 1, kb + 64);   // stays in flight across this compute
    char* ks = smem + buf * 8192;
    char* vs = smem + 16384 + buf * 8192;
    const bool diag = (kt == qt);
    const int nbmax = diag ? (wave + 1) : 4;

    // S^T = K Q^T : A=K-frag (m=key), B=Q-frag (n=q). C: key=quad*4+r, q=l16.
    f32x4 sf[4];
#pragma unroll
    for (int nb = 0; nb < 4; nb++) {
      if (nb < nbmax) {
        f32x4 s; s[0]=0.f; s[1]=0.f; s[2]=0.f; s[3]=0.f;
#pragma unroll
        for (int kk = 0; kk < 2; kk++) {
          bf16x8 kfr = *(const bf16x8*)(ks + (nb * 16 + l16) * 128 + (((kk * 4 + quad) ^ swz) * 16));
          s = __builtin_amdgcn_mfma_f32_16x16x32_bf16(kfr, qf[kk], s, 0, 0, 0);
        }
        sf[nb] = s;
      } else {
        sf[nb][0] = -1e30f; sf[nb][1] = -1e30f; sf[nb][2] = -1e30f; sf[nb][3] = -1e30f;
      }
    }
    if (diag) {
#pragma unroll
      for (int nb = 0; nb < 4; nb++)
#pragma unroll
        for (int r = 0; r < 4; r++)
          if (kb + nb * 16 + quad * 4 + r > qg) sf[nb][r] = -1e30f;
    }

    // online softmax; q lives in lane (l16), key-partials across quads
    float mx = sf[0][0];
#pragma unroll
    for (int nb = 0; nb < 4; nb++)
#pragma unroll
      for (int r = 0; r < 4; r++) mx = fmaxf(mx, sf[nb][r]);
    mx = fmaxf(mx, __shfl_xor(mx, 16));
    mx = fmaxf(mx, __shfl_xor(mx, 32));
    const float mnew = fmaxf(mI, mx);
    const float c1 = 0.18033688011f;  // log2(e)/8
    const float mc = mnew * c1;
    const float alpha = __builtin_amdgcn_exp2f(mI * c1 - mc);
    mI = mnew;
    float ls = 0.f;
#pragma unroll
    for (int nb = 0; nb < 4; nb++)
#pragma unroll
      for (int r = 0; r < 4; r++) {
        const float p2 = __builtin_amdgcn_exp2f(sf[nb][r] * c1 - mc);
        sf[nb][r] = p2;
        ls += p2;
      }
    lI = lI * alpha + ls;   // lane-local partial; reduced at end
#pragma unroll
    for (int db = 0; db < 4; db++)
#pragma unroll
      for (int r = 0; r < 4; r++) o[db][r] *= alpha;

    // P^T -> Ps (row=q(l16), 64 keys, swizzled chunks); vectorized b64 writes
#pragma unroll
    for (int nb = 0; nb < 4; nb++) {
      uint2 pv;
      pv.x = pk2(sf[nb][0], sf[nb][1]);
      pv.y = pk2(sf[nb][2], sf[nb][3]);
      *(uint2*)(ps + l16 * 128 + (((nb * 2 + (quad >> 1)) ^ swz) * 16) + (quad & 1) * 8) = pv;
    }
    // wave-private region: compiler's lgkmcnt ordering suffices, no barrier.

    // O^T += V^T P^T : A=V-frag (m=d), B=P-frag (n=q)
    const int kkmax = diag ? ((wave >> 1) + 1) : 2;
    for (int kk = 0; kk < kkmax; kk++) {
      bf16x8 pf = *(const bf16x8*)(ps + l16 * 128 + (((kk * 4 + quad) ^ swz) * 16));
#pragma unroll
      for (int db = 0; db < 4; db++) {
        bf16x8 vf = *(const bf16x8*)(vs + (db * 16 + l16) * 128 + (((kk * 4 + quad) ^ swz) * 16));
        o[db] = __builtin_amdgcn_mfma_f32_16x16x32_bf16(vf, pf, o[db], 0, 0, 0);
      }
    }
  }
#undef STAGE

  // final l reduction across quads, normalize, store At (b,s,h,d)
  lI += __shfl_xor(lI, 16);
  lI += __shfl_xor(lI, 32);
  const float invl = 1.0f / lI;
  const int b = bh >> 4, h = bh & 15;
  unsigned short* orow = Oa + ((uint64_t)(b * SEQ + qg)) * DM + h * 64 + quad * 4;
#pragma unroll
  for (int db = 0; db < 4; db++) {
    uint2 w;
    w.x = pk2(o[db][0] * invl, o[db][1] * invl);
    w.y = pk2(o[db][2] * invl, o[db][3] * invl);
    *(uint2*)(orow + db * 16) = w;
  }
}

extern "C" void kernel_launch(void* const* d_in, const int* in_sizes, int n_in,
                              void* d_out, int out_size, void* d_ws, size_t ws_size,
                              hipStream_t stream) {
  const float* x  = (const float*)d_in[0];
  const int* tp   = (const int*)d_in[1];
  const float* wq = (const float*)d_in[2];
  const float* wk = (const float*)d_in[3];
  const float* wv = (const float*)d_in[4];
  const float* wo = (const float*)d_in[5];
  float* out = (float*)d_out;

  unsigned short* ws = (unsigned short*)d_ws;
  unsigned short* xb  = ws;                   // (b,s,dm) bf16        8 MB
  unsigned short* w3b = ws + 4194304;         // [wq;wk;wv] 3072x1024 6 MB
  unsigned short* wob = ws + 7340032;         // 2 MB
  unsigned short* Qr  = ws + 8388608;         // (b,h,s,64)  8 MB
  unsigned short* Kr  = ws + 12582912;        // (b,h,s,64)  8 MB
  unsigned short* Vt  = ws + 16777216;        // (b,h,64,s)  8 MB
  unsigned short* At  = ws + 20971520;        // (b,s,h*64)  8 MB

  cvt_all<<<8192, 256, 0, stream>>>(x, wq, wk, wv, wo, ws);
  gemm_qkv<<<dim3(24, 32), 256, 0, stream>>>(xb, w3b, Qr, Kr, Vt, tp);
  flash_attn<<<1024, 256, 0, stream>>>(Qr, Kr, Vt, At);
  gemm_ao<<<dim3(16, 32), 256, 0, stream>>>(At, wob, out);
}